// Round 1
// 132.191 us; speedup vs baseline: 1.0634x; 1.0634x over previous
//
#include <hip/hip_runtime.h>
#include <cstddef>

// N=8, C=128, L=512, D=64, F=512, ATTN_W=64

// ---------------------------------------------------------------------------
// Kernel 1: prep = transpose_in + q/k projection. grid 512, block 256.
// Block = (n, l-tile of 16, which). which=0: q via Wt (+ xt write); which=1: k.
// ---------------------------------------------------------------------------
__global__ __launch_bounds__(256) void prep_kernel(
    const float* __restrict__ x, const float* __restrict__ Wt,
    const float* __restrict__ Wx, float* __restrict__ xt,
    float* __restrict__ q, float* __restrict__ k) {
  __shared__ float xs[128][17];
  int tid = threadIdx.x;
  int bz = blockIdx.x;
  int n = bz >> 6;
  int t6 = bz & 63;
  int l0 = (t6 >> 1) << 4;
  int which = t6 & 1;

  for (int idx = tid; idx < 512; idx += 256) {
    int c = idx >> 2, v = idx & 3;
    float4 d4 = *(const float4*)(x + ((size_t)n * 128 + c) * 512 + l0 + 4 * v);
    xs[c][4 * v + 0] = d4.x; xs[c][4 * v + 1] = d4.y;
    xs[c][4 * v + 2] = d4.z; xs[c][4 * v + 3] = d4.w;
  }
  __syncthreads();

  if (which == 0) {
    for (int idx = tid; idx < 2048; idx += 256) {
      int c = idx & 127, jj = idx >> 7;
      xt[((size_t)n * 512 + l0 + jj) * 128 + c] = xs[c][jj];
    }
  }

  const float* W = which ? Wx : Wt;
  float* dst = which ? k : q;
  int r = tid >> 4;          // 0..15
  int f0 = (tid & 15) << 2;  // 0..60
  float acc[4] = {0.f, 0.f, 0.f, 0.f};
#pragma unroll 4
  for (int cc = 0; cc < 128; cc++) {
    float xv = xs[cc][r];
    float4 w = *(const float4*)(W + cc * 64 + f0);
    acc[0] += xv * w.x; acc[1] += xv * w.y;
    acc[2] += xv * w.z; acc[3] += xv * w.w;
  }
  *(float4*)(dst + ((size_t)n * 512 + l0 + r) * 64 + f0) =
      make_float4(acc[0], acc[1], acc[2], acc[3]);
}

// ---------------------------------------------------------------------------
// Kernel 2: FULLY FUSED attn (scores+softmax+a+v+LN0) + FFN + LN1 + transposed
// write. 16 rows/block, grid 256 (1 block/CU), block 512.
// x2 never leaves LDS: attn writes xst[c][r] directly; FFN consumes it.
// LDS phases alias: attn's ks/qs (24.6 KB) region is reused by FFN's
// tst/part/ys (80 KB). Total 96.5 KB -> 1 block/CU.
// ---------------------------------------------------------------------------
__global__ __launch_bounds__(512, 2) void attn_ffn_fused_kernel(
    const float* __restrict__ q, const float* __restrict__ k,
    const float* __restrict__ bh, const float* __restrict__ Wa,
    const float* __restrict__ ba, const float* __restrict__ xt,
    const float* __restrict__ g0, const float* __restrict__ be0,
    const float* __restrict__ W0, const float* __restrict__ b0,
    const float* __restrict__ W1, const float* __restrict__ b1,
    const float* __restrict__ g1, const float* __restrict__ be1,
    float* __restrict__ a, float* __restrict__ out) {
  // phase-aliased scratch: [A] ks[79][65] (20540 B) + qs[16][64] (4096 B)
  //                        [C] tst[512][20] (40960) + part[4][16][128] (32768)
  //                            + ys[16][128] (8192)
  __shared__ __align__(16) char smem[81920];
  __shared__ float xst[128][20];  // x2 tile, [c][r], live A->end
  __shared__ float av[16][64];    // softmax weights, live A->B
  __shared__ float was[64];

  float (*ks)[65] = (float(*)[65])smem;              // [79][65]
  float (*qs)[64] = (float(*)[64])(smem + 20544);    // [16][64]
  float (*tst)[20] = (float(*)[20])smem;             // [512][20]
  float (*part)[16][128] = (float(*)[16][128])(smem + 40960);  // [4][16][128]
  float (*ys)[128] = (float(*)[128])(smem + 73728);  // [16][128]

  int tid = threadIdx.x;
  int w = tid >> 6, lane = tid & 63;
  size_t rbase = (size_t)blockIdx.x * 16;
  int n = (int)(rbase >> 9);
  int i0 = (int)(rbase & 511);
  int jlo0 = i0 - 32;

  // ---- Phase A: load q (+bh), banded k window ----
  if (tid < 64) was[tid] = Wa[tid];
  for (int idx = tid; idx < 16 * 16; idx += 512) {
    int r = idx >> 4, d4 = (idx & 15) << 2;
    float4 qv = *(const float4*)(q + ((size_t)n * 512 + i0 + r) * 64 + d4);
    float4 bv = *(const float4*)(bh + d4);
    *(float4*)(&qs[r][d4]) =
        make_float4(qv.x + bv.x, qv.y + bv.y, qv.z + bv.z, qv.w + bv.w);
  }
  for (int idx = tid; idx < 79 * 16; idx += 512) {
    int row = idx >> 4, d4 = (idx & 15) << 2;
    int j = jlo0 + row;
    float4 v = make_float4(0.f, 0.f, 0.f, 0.f);
    if (j >= 0 && j < 512)
      v = *(const float4*)(k + ((size_t)n * 512 + j) * 64 + d4);
    ks[row][d4 + 0] = v.x; ks[row][d4 + 1] = v.y;
    ks[row][d4 + 2] = v.z; ks[row][d4 + 3] = v.w;
  }
  __syncthreads();

  // ---- Phase A2: scores + softmax + a-write. Wave w: rows 2w, 2w+1 ----
#pragma unroll
  for (int rr = 0; rr < 2; rr++) {
    int r = 2 * w + rr;
    int i = i0 + r;
    int j = jlo0 + r + lane;
    bool valid = (j >= 0 && j < 512);
    const float* krow = &ks[r + lane][0];  // stride 65: conflict-free
    float e = 0.f;
#pragma unroll 8
    for (int d = 0; d < 64; d++) {
      float hx = qs[r][d] + krow[d];
      float ex2 = __expf(2.f * hx);
      float th = 1.f - 2.f * __builtin_amdgcn_rcpf(ex2 + 1.f);  // tanh
      e += was[d] * th;
    }
    e += ba[0];
    if (!valid) e = -1e30f;

    float m = e;
    for (int o = 32; o > 0; o >>= 1) m = fmaxf(m, __shfl_xor(m, o, 64));
    float ex = valid ? __expf(e - m) : 0.f;
    float s = ex;
    for (int o = 32; o > 0; o >>= 1) s += __shfl_xor(s, o, 64);
    av[r][lane] = ex / (s + 1e-6f);

    float* arow = a + ((size_t)n * 512 + i) * 512;
    int jlo = i - 32;
#pragma unroll
    for (int t = 0; t < 2; t++) {
      int col0 = 4 * lane + 256 * t;
      float4 v;
      { int jr = col0 + 0 - jlo; int jc = min(max(jr, 0), 63); v.x = (jr >= 0 && jr < 64) ? av[r][jc] : 0.f; }
      { int jr = col0 + 1 - jlo; int jc = min(max(jr, 0), 63); v.y = (jr >= 0 && jr < 64) ? av[r][jc] : 0.f; }
      { int jr = col0 + 2 - jlo; int jc = min(max(jr, 0), 63); v.z = (jr >= 0 && jr < 64) ? av[r][jc] : 0.f; }
      { int jr = col0 + 3 - jlo; int jc = min(max(jr, 0), 63); v.w = (jr >= 0 && jr < 64) ? av[r][jc] : 0.f; }
      *(float4*)(arow + col0) = v;
    }
  }
  __syncthreads();

  // ---- Phase B: v = a@xt + residual -> raw y into xst[c][r] ----
  {
    int c = tid & 127;
    int rq = tid >> 7;  // 0..3 -> rows 4rq..4rq+3
    int r0 = rq << 2;
    const float* xtn = xt + (size_t)n * 512 * 128;
    float acc[4] = {0.f, 0.f, 0.f, 0.f};
    int jlo = i0 + r0 - 32;
#pragma unroll
    for (int mm = 0; mm < 67; mm++) {
      int jj = jlo + mm;
      int jc = min(max(jj, 0), 511);
      float xv = xtn[(size_t)jc * 128 + c];
#pragma unroll
      for (int rr = 0; rr < 4; rr++) {
        int mr = mm - rr;
        if (mr >= 0 && mr < 64) acc[rr] += av[r0 + rr][mr] * xv;  // av==0 OOB
      }
    }
#pragma unroll
    for (int rr = 0; rr < 4; rr++) {
      float res = xtn[(size_t)(i0 + r0 + rr) * 128 + c];
      xst[c][r0 + rr] = acc[rr] + res;
    }
  }
  __syncthreads();

  // ---- Phase B2: LN0 in place on xst. 8 waves x 2 rows ----
#pragma unroll
  for (int rr = 2 * w; rr <= 2 * w + 1; rr++) {
    float a0 = xst[lane][rr], a1 = xst[lane + 64][rr];
    float s = a0 + a1, s2 = a0 * a0 + a1 * a1;
    for (int o = 32; o > 0; o >>= 1) {
      s += __shfl_xor(s, o, 64);
      s2 += __shfl_xor(s2, o, 64);
    }
    float mu = s * (1.f / 128.f);
    float var = s2 * (1.f / 128.f) - mu * mu;
    float rs = rsqrtf(var + 1e-5f);
    xst[lane][rr] = (a0 - mu) * rs * g0[lane] + be0[lane];
    xst[lane + 64][rr] = (a1 - mu) * rs * g0[lane + 64] + be0[lane + 64];
  }
  __syncthreads();

  // ---- Phase C: FFN GEMM1 + bias + relu -> tst (aliases ks/qs) ----
  {
    int fb = tid & 127;
    int r0 = (tid >> 7) << 2;  // 0,4,8,12
    float acc[4][4];
#pragma unroll
    for (int i = 0; i < 4; i++)
#pragma unroll
      for (int jj = 0; jj < 4; jj++) acc[i][jj] = 0.f;
#pragma unroll 4
    for (int cc = 0; cc < 128; cc++) {
      float4 xv = *(const float4*)(&xst[cc][r0]);  // broadcast (4 addrs)
      float w0 = W0[cc * 512 + fb];
      float w1 = W0[cc * 512 + fb + 128];
      float w2 = W0[cc * 512 + fb + 256];
      float w3 = W0[cc * 512 + fb + 384];
      acc[0][0] += xv.x * w0; acc[1][0] += xv.y * w0; acc[2][0] += xv.z * w0; acc[3][0] += xv.w * w0;
      acc[0][1] += xv.x * w1; acc[1][1] += xv.y * w1; acc[2][1] += xv.z * w1; acc[3][1] += xv.w * w1;
      acc[0][2] += xv.x * w2; acc[1][2] += xv.y * w2; acc[2][2] += xv.z * w2; acc[3][2] += xv.w * w2;
      acc[0][3] += xv.x * w3; acc[1][3] += xv.y * w3; acc[2][3] += xv.z * w3; acc[3][3] += xv.w * w3;
    }
#pragma unroll
    for (int jj = 0; jj < 4; jj++) {
      int f = fb + 128 * jj;
      float bb = b0[f];
      float4 v = make_float4(fmaxf(acc[0][jj] + bb, 0.f), fmaxf(acc[1][jj] + bb, 0.f),
                             fmaxf(acc[2][jj] + bb, 0.f), fmaxf(acc[3][jj] + bb, 0.f));
      *(float4*)(&tst[f][r0]) = v;
    }
  }
  __syncthreads();

  // ---- Phase C2: GEMM2 (K-split x4) -> part ----
  {
    int kq = tid >> 7;               // 0..3
    int c0 = (tid & 31) << 2;        // 0..124
    int r0 = ((tid >> 5) & 3) << 2;  // 0,4,8,12
    float acc[4][4];
#pragma unroll
    for (int i = 0; i < 4; i++)
#pragma unroll
      for (int jj = 0; jj < 4; jj++) acc[i][jj] = 0.f;
    const float* W1p = W1 + (size_t)kq * 128 * 128;
    const float(*tstp)[20] = &tst[kq * 128];
#pragma unroll 4
    for (int t = 0; t < 128; t++) {
      float4 wv = *(const float4*)(W1p + t * 128 + c0);
      float4 tv = *(const float4*)(&tstp[t][r0]);  // broadcast (4 addrs)
      acc[0][0] += tv.x * wv.x; acc[0][1] += tv.x * wv.y; acc[0][2] += tv.x * wv.z; acc[0][3] += tv.x * wv.w;
      acc[1][0] += tv.y * wv.x; acc[1][1] += tv.y * wv.y; acc[1][2] += tv.y * wv.z; acc[1][3] += tv.y * wv.w;
      acc[2][0] += tv.z * wv.x; acc[2][1] += tv.z * wv.y; acc[2][2] += tv.z * wv.z; acc[2][3] += tv.z * wv.w;
      acc[3][0] += tv.w * wv.x; acc[3][1] += tv.w * wv.y; acc[3][2] += tv.w * wv.z; acc[3][3] += tv.w * wv.w;
    }
#pragma unroll
    for (int i = 0; i < 4; i++) {
      *(float4*)(&part[kq][r0 + i][c0]) =
          make_float4(acc[i][0], acc[i][1], acc[i][2], acc[i][3]);
    }
  }
  __syncthreads();

  for (int idx = tid; idx < 2048; idx += 512) {
    int r = idx >> 7, c = idx & 127;
    ys[r][c] = part[0][r][c] + part[1][r][c] + part[2][r][c] + part[3][r][c] +
               b1[c] + xst[c][r];
  }
  __syncthreads();

  // ---- LN1: 8 waves x 2 rows ----
#pragma unroll
  for (int rr = 2 * w; rr <= 2 * w + 1; rr++) {
    float a0 = ys[rr][lane], a1 = ys[rr][lane + 64];
    float s = a0 + a1, s2 = a0 * a0 + a1 * a1;
    for (int o = 32; o > 0; o >>= 1) {
      s += __shfl_xor(s, o, 64);
      s2 += __shfl_xor(s2, o, 64);
    }
    float mu = s * (1.f / 128.f);
    float var = s2 * (1.f / 128.f) - mu * mu;
    float rs = rsqrtf(var + 1e-5f);
    ys[rr][lane] = (a0 - mu) * rs * g1[lane] + be1[lane];
    ys[rr][lane + 64] = (a1 - mu) * rs * g1[lane + 64] + be1[lane + 64];
  }
  __syncthreads();

  // ---- transposed write: out (N,C,L); 16 consecutive l per c ----
  {
    int c = tid >> 2, tq = tid & 3;
    int l0 = (int)(rbase & 511);
    float4 v = make_float4(ys[4 * tq + 0][c], ys[4 * tq + 1][c],
                           ys[4 * tq + 2][c], ys[4 * tq + 3][c]);
    *(float4*)(out + ((size_t)n * 128 + c) * 512 + l0 + 4 * tq) = v;
  }
}

// ---------------------------------------------------------------------------
extern "C" void kernel_launch(void* const* d_in, const int* in_sizes, int n_in,
                              void* d_out, int out_size, void* d_ws, size_t ws_size,
                              hipStream_t stream) {
  const float* x   = (const float*)d_in[0];
  const float* Wx  = (const float*)d_in[1];
  const float* Wt  = (const float*)d_in[2];
  const float* bh  = (const float*)d_in[3];
  const float* Wa  = (const float*)d_in[4];
  const float* ba  = (const float*)d_in[5];
  const float* W0  = (const float*)d_in[6];
  const float* b0  = (const float*)d_in[7];
  const float* W1  = (const float*)d_in[8];
  const float* b1  = (const float*)d_in[9];
  const float* g0  = (const float*)d_in[10];
  const float* be0 = (const float*)d_in[11];
  const float* g1  = (const float*)d_in[12];
  const float* be1 = (const float*)d_in[13];

  float* outx = (float*)d_out;           // N*C*L = 524288
  float* outa = outx + (size_t)524288;   // N*L*L = 2097152

  float* ws = (float*)d_ws;
  float* xt = ws;              // 524288
  float* q  = xt + 524288;     // 262144
  float* k  = q + 262144;      // 262144

  prep_kernel<<<512, 256, 0, stream>>>(x, Wt, Wx, xt, q, k);
  attn_ffn_fused_kernel<<<256, 512, 0, stream>>>(
      q, k, bh, Wa, ba, xt, g0, be0, W0, b0, W1, b1, g1, be1, outa, outx);
}

// Round 2
// 127.099 us; speedup vs baseline: 1.1060x; 1.0401x over previous
//
#include <hip/hip_runtime.h>
#include <cstddef>

// N=8, C=128, L=512, D=64, F=512, ATTN_W=64

// ---------------------------------------------------------------------------
// Kernel 1: prep = transpose_in + q/k projection. grid 512, block 256.
// Block = (n, l-tile of 16, which). which=0: q via Wt (+ xt write); which=1: k.
// ---------------------------------------------------------------------------
__global__ __launch_bounds__(256) void prep_kernel(
    const float* __restrict__ x, const float* __restrict__ Wt,
    const float* __restrict__ Wx, float* __restrict__ xt,
    float* __restrict__ q, float* __restrict__ k) {
  __shared__ float xs[128][17];
  int tid = threadIdx.x;
  int bz = blockIdx.x;
  int n = bz >> 6;
  int t6 = bz & 63;
  int l0 = (t6 >> 1) << 4;
  int which = t6 & 1;

  for (int idx = tid; idx < 512; idx += 256) {
    int c = idx >> 2, v = idx & 3;
    float4 d4 = *(const float4*)(x + ((size_t)n * 128 + c) * 512 + l0 + 4 * v);
    xs[c][4 * v + 0] = d4.x; xs[c][4 * v + 1] = d4.y;
    xs[c][4 * v + 2] = d4.z; xs[c][4 * v + 3] = d4.w;
  }
  __syncthreads();

  if (which == 0) {
    for (int idx = tid; idx < 2048; idx += 256) {
      int c = idx & 127, jj = idx >> 7;
      xt[((size_t)n * 512 + l0 + jj) * 128 + c] = xs[c][jj];
    }
  }

  const float* W = which ? Wx : Wt;
  float* dst = which ? k : q;
  int r = tid >> 4;          // 0..15
  int f0 = (tid & 15) << 2;  // 0..60
  float acc[4] = {0.f, 0.f, 0.f, 0.f};
#pragma unroll 4
  for (int cc = 0; cc < 128; cc++) {
    float xv = xs[cc][r];
    float4 w = *(const float4*)(W + cc * 64 + f0);
    acc[0] += xv * w.x; acc[1] += xv * w.y;
    acc[2] += xv * w.z; acc[3] += xv * w.w;
  }
  *(float4*)(dst + ((size_t)n * 512 + l0 + r) * 64 + f0) =
      make_float4(acc[0], acc[1], acc[2], acc[3]);
}

// ---------------------------------------------------------------------------
// Kernel 2: FULLY FUSED attn+FFN. 8 rows/block, grid 512 (2 blocks/CU),
// block 256. LDS ~43.5 KB so two blocks co-reside: when one block sits at a
// phase barrier, the other block's waves issue -> hides the barrier drains.
// Layouts chosen conflict-free: tst[r][f], xst[r][c] (writes lane-consecutive,
// reads wave-broadcast). W0 loads vectorized float4.
// ---------------------------------------------------------------------------
__global__ __launch_bounds__(256, 2) void attn_ffn_fused_kernel(
    const float* __restrict__ q, const float* __restrict__ k,
    const float* __restrict__ bh, const float* __restrict__ Wa,
    const float* __restrict__ ba, const float* __restrict__ xt,
    const float* __restrict__ g0, const float* __restrict__ be0,
    const float* __restrict__ W0, const float* __restrict__ b0,
    const float* __restrict__ W1, const float* __restrict__ b1,
    const float* __restrict__ g1, const float* __restrict__ be1,
    float* __restrict__ a, float* __restrict__ out) {
  // Aliased scratch:
  //  Phase A: ks[71][65] @0 (18460 B), qs[8][64] @18464 (2048 B)
  //  Phase C: tst[8][516] @0 (16512 B), part[4][8][128] @16512 (16384 B),
  //           ys[8][128] @32896 (4096 B)  -> alias region 36992 B
  __shared__ __align__(16) char smem[36992];
  __shared__ float xst[8][132];  // x2 tile [r][c], live B -> end
  __shared__ float av[8][64];    // softmax weights, live A2 -> B
  __shared__ float was[64];

  float (*ks)[65] = (float(*)[65])smem;            // [71][65]
  float (*qs)[64] = (float(*)[64])(smem + 18464);  // [8][64]
  float (*tst)[516] = (float(*)[516])smem;         // [8][516]
  float (*part)[8][128] = (float(*)[8][128])(smem + 16512);  // [4][8][128]
  float (*ys)[128] = (float(*)[128])(smem + 32896);          // [8][128]

  int tid = threadIdx.x;
  int w = tid >> 6, lane = tid & 63;
  size_t rbase = (size_t)blockIdx.x * 8;
  int n = (int)(rbase >> 9);
  int i0 = (int)(rbase & 511);
  int jlo0 = i0 - 32;

  // ---- Phase A: load q (+bh), banded k window ----
  if (tid < 64) was[tid] = Wa[tid];
  if (tid < 128) {
    int r = tid >> 4, d4 = (tid & 15) << 2;
    float4 qv = *(const float4*)(q + ((size_t)n * 512 + i0 + r) * 64 + d4);
    float4 bv = *(const float4*)(bh + d4);
    *(float4*)(&qs[r][d4]) =
        make_float4(qv.x + bv.x, qv.y + bv.y, qv.z + bv.z, qv.w + bv.w);
  }
  for (int idx = tid; idx < 71 * 16; idx += 256) {
    int row = idx >> 4, d4 = (idx & 15) << 2;
    int j = jlo0 + row;
    float4 v = make_float4(0.f, 0.f, 0.f, 0.f);
    if (j >= 0 && j < 512)
      v = *(const float4*)(k + ((size_t)n * 512 + j) * 64 + d4);
    ks[row][d4 + 0] = v.x; ks[row][d4 + 1] = v.y;
    ks[row][d4 + 2] = v.z; ks[row][d4 + 3] = v.w;
  }
  __syncthreads();

  // ---- Phase A2: scores + softmax + a-write. Wave w: rows 2w, 2w+1 ----
#pragma unroll
  for (int rr = 0; rr < 2; rr++) {
    int r = 2 * w + rr;
    int i = i0 + r;
    int j = jlo0 + r + lane;
    bool valid = (j >= 0 && j < 512);
    const float* krow = &ks[r + lane][0];  // stride 65: 2-way (free)
    float e = 0.f;
#pragma unroll 8
    for (int d = 0; d < 64; d++) {
      float hx = qs[r][d] + krow[d];
      float ex2 = __expf(2.f * hx);
      float th = 1.f - 2.f * __builtin_amdgcn_rcpf(ex2 + 1.f);  // tanh
      e += was[d] * th;
    }
    e += ba[0];
    if (!valid) e = -1e30f;

    float m = e;
    for (int o = 32; o > 0; o >>= 1) m = fmaxf(m, __shfl_xor(m, o, 64));
    float ex = valid ? __expf(e - m) : 0.f;
    float s = ex;
    for (int o = 32; o > 0; o >>= 1) s += __shfl_xor(s, o, 64);
    av[r][lane] = ex / (s + 1e-6f);

    float* arow = a + ((size_t)n * 512 + i) * 512;
    int jlo = i - 32;
#pragma unroll
    for (int t = 0; t < 2; t++) {
      int col0 = 4 * lane + 256 * t;
      float4 v;
      { int jr = col0 + 0 - jlo; int jc = min(max(jr, 0), 63); v.x = (jr >= 0 && jr < 64) ? av[r][jc] : 0.f; }
      { int jr = col0 + 1 - jlo; int jc = min(max(jr, 0), 63); v.y = (jr >= 0 && jr < 64) ? av[r][jc] : 0.f; }
      { int jr = col0 + 2 - jlo; int jc = min(max(jr, 0), 63); v.z = (jr >= 0 && jr < 64) ? av[r][jc] : 0.f; }
      { int jr = col0 + 3 - jlo; int jc = min(max(jr, 0), 63); v.w = (jr >= 0 && jr < 64) ? av[r][jc] : 0.f; }
      *(float4*)(arow + col0) = v;
    }
  }
  __syncthreads();

  // ---- Phase B: v = a@xt + residual -> raw y into xst[r][c] ----
  {
    int c = tid & 127;
    int r0 = (tid >> 7) << 2;  // 0 or 4
    const float* xtn = xt + (size_t)n * 512 * 128;
    float acc[4] = {0.f, 0.f, 0.f, 0.f};
    int jlo = i0 + r0 - 32;
#pragma unroll
    for (int mm = 0; mm < 67; mm++) {
      int jj = jlo + mm;
      int jc = min(max(jj, 0), 511);
      float xv = xtn[(size_t)jc * 128 + c];
#pragma unroll
      for (int rr = 0; rr < 4; rr++) {
        int mr = mm - rr;
        if (mr >= 0 && mr < 64) acc[rr] += av[r0 + rr][mr] * xv;  // av==0 OOB
      }
    }
#pragma unroll
    for (int rr = 0; rr < 4; rr++) {
      float res = xtn[(size_t)(i0 + r0 + rr) * 128 + c];
      xst[r0 + rr][c] = acc[rr] + res;  // lane-consecutive c: conflict-free
    }
  }
  __syncthreads();

  // ---- Phase B2: LN0 in place on xst. 4 waves x 2 rows ----
#pragma unroll
  for (int rr = 2 * w; rr <= 2 * w + 1; rr++) {
    float a0 = xst[rr][lane], a1 = xst[rr][lane + 64];
    float s = a0 + a1, s2 = a0 * a0 + a1 * a1;
    for (int o = 32; o > 0; o >>= 1) {
      s += __shfl_xor(s, o, 64);
      s2 += __shfl_xor(s2, o, 64);
    }
    float mu = s * (1.f / 128.f);
    float var = s2 * (1.f / 128.f) - mu * mu;
    float rs = rsqrtf(var + 1e-5f);
    xst[rr][lane] = (a0 - mu) * rs * g0[lane] + be0[lane];
    xst[rr][lane + 64] = (a1 - mu) * rs * g0[lane + 64] + be0[lane + 64];
  }
  __syncthreads();

  // ---- Phase C: FFN GEMM1 + bias + relu -> tst[r][f] (aliases ks/qs) ----
  {
    int f0 = (tid & 127) << 2;  // 0..508, float4 of consecutive f
    int r0 = (tid >> 7) << 2;   // 0 or 4
    float acc[4][4];
#pragma unroll
    for (int i = 0; i < 4; i++)
#pragma unroll
      for (int jj = 0; jj < 4; jj++) acc[i][jj] = 0.f;
#pragma unroll 4
    for (int cc = 0; cc < 128; cc++) {
      float4 wv = *(const float4*)(W0 + cc * 512 + f0);  // coalesced 16B/lane
      float x0 = xst[r0 + 0][cc];  // wave-broadcast: free
      float x1 = xst[r0 + 1][cc];
      float x2v = xst[r0 + 2][cc];
      float x3 = xst[r0 + 3][cc];
      acc[0][0] += x0 * wv.x; acc[0][1] += x0 * wv.y; acc[0][2] += x0 * wv.z; acc[0][3] += x0 * wv.w;
      acc[1][0] += x1 * wv.x; acc[1][1] += x1 * wv.y; acc[1][2] += x1 * wv.z; acc[1][3] += x1 * wv.w;
      acc[2][0] += x2v * wv.x; acc[2][1] += x2v * wv.y; acc[2][2] += x2v * wv.z; acc[2][3] += x2v * wv.w;
      acc[3][0] += x3 * wv.x; acc[3][1] += x3 * wv.y; acc[3][2] += x3 * wv.z; acc[3][3] += x3 * wv.w;
    }
    float4 bb = *(const float4*)(b0 + f0);
#pragma unroll
    for (int rr = 0; rr < 4; rr++) {
      float4 v = make_float4(fmaxf(acc[rr][0] + bb.x, 0.f), fmaxf(acc[rr][1] + bb.y, 0.f),
                             fmaxf(acc[rr][2] + bb.z, 0.f), fmaxf(acc[rr][3] + bb.w, 0.f));
      *(float4*)(&tst[r0 + rr][f0]) = v;  // lane-consecutive: conflict-free
    }
  }
  __syncthreads();

  // ---- Phase C2: GEMM2 (K-split x4 across waves) -> part ----
  {
    int kq = tid >> 6;               // wave id 0..3 = K-quarter
    int c0 = (lane & 31) << 2;       // 0..124
    int r0 = (lane >> 5) << 2;       // 0 or 4
    float acc[4][4];
#pragma unroll
    for (int i = 0; i < 4; i++)
#pragma unroll
      for (int jj = 0; jj < 4; jj++) acc[i][jj] = 0.f;
#pragma unroll 2
    for (int tb = 0; tb < 128; tb += 4) {
      int tt = kq * 128 + tb;
      float4 tv0 = *(const float4*)(&tst[r0 + 0][tt]);  // broadcast b128
      float4 tv1 = *(const float4*)(&tst[r0 + 1][tt]);
      float4 tv2 = *(const float4*)(&tst[r0 + 2][tt]);
      float4 tv3 = *(const float4*)(&tst[r0 + 3][tt]);
#pragma unroll
      for (int u = 0; u < 4; u++) {
        float4 wv = *(const float4*)(W1 + (size_t)(tt + u) * 128 + c0);
        float t0 = (&tv0.x)[u], t1 = (&tv1.x)[u], t2 = (&tv2.x)[u], t3 = (&tv3.x)[u];
        acc[0][0] += t0 * wv.x; acc[0][1] += t0 * wv.y; acc[0][2] += t0 * wv.z; acc[0][3] += t0 * wv.w;
        acc[1][0] += t1 * wv.x; acc[1][1] += t1 * wv.y; acc[1][2] += t1 * wv.z; acc[1][3] += t1 * wv.w;
        acc[2][0] += t2 * wv.x; acc[2][1] += t2 * wv.y; acc[2][2] += t2 * wv.z; acc[2][3] += t2 * wv.w;
        acc[3][0] += t3 * wv.x; acc[3][1] += t3 * wv.y; acc[3][2] += t3 * wv.z; acc[3][3] += t3 * wv.w;
      }
    }
#pragma unroll
    for (int i = 0; i < 4; i++) {
      *(float4*)(&part[kq][r0 + i][c0]) =
          make_float4(acc[i][0], acc[i][1], acc[i][2], acc[i][3]);
    }
  }
  __syncthreads();

  // ---- combine partials + bias + residual ----
  for (int idx = tid; idx < 1024; idx += 256) {
    int r = idx >> 7, c = idx & 127;
    ys[r][c] = part[0][r][c] + part[1][r][c] + part[2][r][c] + part[3][r][c] +
               b1[c] + xst[r][c];
  }
  __syncthreads();

  // ---- LN1: 4 waves x 2 rows ----
#pragma unroll
  for (int rr = 2 * w; rr <= 2 * w + 1; rr++) {
    float a0 = ys[rr][lane], a1 = ys[rr][lane + 64];
    float s = a0 + a1, s2 = a0 * a0 + a1 * a1;
    for (int o = 32; o > 0; o >>= 1) {
      s += __shfl_xor(s, o, 64);
      s2 += __shfl_xor(s2, o, 64);
    }
    float mu = s * (1.f / 128.f);
    float var = s2 * (1.f / 128.f) - mu * mu;
    float rs = rsqrtf(var + 1e-5f);
    ys[rr][lane] = (a0 - mu) * rs * g1[lane] + be1[lane];
    ys[rr][lane + 64] = (a1 - mu) * rs * g1[lane + 64] + be1[lane + 64];
  }
  __syncthreads();

  // ---- transposed write: out (N,C,L); 8 consecutive l per c ----
  {
    int c = tid >> 1, tq = tid & 1;
    int l0 = (int)(rbase & 511);
    float4 v = make_float4(ys[4 * tq + 0][c], ys[4 * tq + 1][c],
                           ys[4 * tq + 2][c], ys[4 * tq + 3][c]);
    *(float4*)(out + ((size_t)n * 128 + c) * 512 + l0 + 4 * tq) = v;
  }
}

// ---------------------------------------------------------------------------
extern "C" void kernel_launch(void* const* d_in, const int* in_sizes, int n_in,
                              void* d_out, int out_size, void* d_ws, size_t ws_size,
                              hipStream_t stream) {
  const float* x   = (const float*)d_in[0];
  const float* Wx  = (const float*)d_in[1];
  const float* Wt  = (const float*)d_in[2];
  const float* bh  = (const float*)d_in[3];
  const float* Wa  = (const float*)d_in[4];
  const float* ba  = (const float*)d_in[5];
  const float* W0  = (const float*)d_in[6];
  const float* b0  = (const float*)d_in[7];
  const float* W1  = (const float*)d_in[8];
  const float* b1  = (const float*)d_in[9];
  const float* g0  = (const float*)d_in[10];
  const float* be0 = (const float*)d_in[11];
  const float* g1  = (const float*)d_in[12];
  const float* be1 = (const float*)d_in[13];

  float* outx = (float*)d_out;           // N*C*L = 524288
  float* outa = outx + (size_t)524288;   // N*L*L = 2097152

  float* ws = (float*)d_ws;
  float* xt = ws;              // 524288
  float* q  = xt + 524288;     // 262144
  float* k  = q + 262144;      // 262144

  prep_kernel<<<512, 256, 0, stream>>>(x, Wt, Wx, xt, q, k);
  attn_ffn_fused_kernel<<<512, 256, 0, stream>>>(
      q, k, bh, Wa, ba, xt, g0, be0, W0, b0, W1, b1, g1, be1, outa, outx);
}

// Round 3
// 124.885 us; speedup vs baseline: 1.1256x; 1.0177x over previous
//
#include <hip/hip_runtime.h>
#include <cstddef>

// N=8, C=128, L=512, D=64, F=512, ATTN_W=64

// ---------------------------------------------------------------------------
// Kernel 1: prep = transpose_in + q/k projection. grid 512, block 256.
// ---------------------------------------------------------------------------
__global__ __launch_bounds__(256) void prep_kernel(
    const float* __restrict__ x, const float* __restrict__ Wt,
    const float* __restrict__ Wx, float* __restrict__ xt,
    float* __restrict__ q, float* __restrict__ k) {
  __shared__ float xs[128][17];
  int tid = threadIdx.x;
  int bz = blockIdx.x;
  int n = bz >> 6;
  int t6 = bz & 63;
  int l0 = (t6 >> 1) << 4;
  int which = t6 & 1;

  for (int idx = tid; idx < 512; idx += 256) {
    int c = idx >> 2, v = idx & 3;
    float4 d4 = *(const float4*)(x + ((size_t)n * 128 + c) * 512 + l0 + 4 * v);
    xs[c][4 * v + 0] = d4.x; xs[c][4 * v + 1] = d4.y;
    xs[c][4 * v + 2] = d4.z; xs[c][4 * v + 3] = d4.w;
  }
  __syncthreads();

  if (which == 0) {
    for (int idx = tid; idx < 2048; idx += 256) {
      int c = idx & 127, jj = idx >> 7;
      xt[((size_t)n * 512 + l0 + jj) * 128 + c] = xs[c][jj];
    }
  }

  const float* W = which ? Wx : Wt;
  float* dst = which ? k : q;
  int r = tid >> 4;          // 0..15
  int f0 = (tid & 15) << 2;  // 0..60
  float acc[4] = {0.f, 0.f, 0.f, 0.f};
#pragma unroll 4
  for (int cc = 0; cc < 128; cc++) {
    float xv = xs[cc][r];
    float4 w = *(const float4*)(W + cc * 64 + f0);
    acc[0] += xv * w.x; acc[1] += xv * w.y;
    acc[2] += xv * w.z; acc[3] += xv * w.w;
  }
  *(float4*)(dst + ((size_t)n * 512 + l0 + r) * 64 + f0) =
      make_float4(acc[0], acc[1], acc[2], acc[3]);
}

// ---------------------------------------------------------------------------
// Kernel 2: FUSED attn+FFN. 8 rows/block, grid 512, block 512 (8 waves).
// 2 blocks/CU x 8 waves = 16 waves/CU (4/SIMD) for latency hiding.
// LDS-instruction minimization:
//   avT[abs_col][row]  -> phase B reads 1 broadcast float2/col (was 4 b32)
//   xstT[c][r]         -> GEMM1 reads 8 rows as 2 b128 broadcast (was 4 b32)
//   tstT[f][r]         -> GEMM2 reads 4 rows as 1 b128 broadcast (was 4 b32)
//   ks stride 68       -> float4 score reads, 16B aligned, conflict-free
// GEMM1: in-wave 4-way K-split + shfl_xor reduce (W0 read 1x per block).
// ---------------------------------------------------------------------------
__global__ __launch_bounds__(512, 4) void attn_ffn_fused_kernel(
    const float* __restrict__ q, const float* __restrict__ k,
    const float* __restrict__ bh, const float* __restrict__ Wa,
    const float* __restrict__ ba, const float* __restrict__ xt,
    const float* __restrict__ g0, const float* __restrict__ be0,
    const float* __restrict__ W0, const float* __restrict__ b0,
    const float* __restrict__ W1, const float* __restrict__ b1,
    const float* __restrict__ g1, const float* __restrict__ be1,
    float* __restrict__ a, float* __restrict__ out) {
  // Aliased region:
  //  Phase A: ks[71][68] @0 (19312 B), qs[8][64] @19328 (2048 B)
  //  Phase C: tstT[512][12] @0 (24576), part[8][8][128] @24576 (32768),
  //           ys[8][128] @57344 (4096) -> 61440 B
  __shared__ __align__(16) char smem[61440];
  __shared__ __align__(16) float xstT[128][12];  // x2 tile [c][r]
  __shared__ __align__(16) float avT[71][10];    // [abs_col][row], skewed
  __shared__ __align__(16) float was[64];

  float (*ks)[68] = (float(*)[68])smem;            // [71][68]
  float (*qs)[64] = (float(*)[64])(smem + 19328);  // [8][64]
  float (*tstT)[12] = (float(*)[12])smem;          // [512][12]
  float (*part)[8][128] = (float(*)[8][128])(smem + 24576);  // [8][8][128]
  float (*ys)[128] = (float(*)[128])(smem + 57344);          // [8][128]

  int tid = threadIdx.x;
  int w = tid >> 6, lane = tid & 63;
  size_t rbase = (size_t)blockIdx.x * 8;
  int n = (int)(rbase >> 9);
  int i0 = (int)(rbase & 511);
  int jlo0 = i0 - 32;

  // ---- Phase A: loads ----
  if (tid < 64) was[tid] = Wa[tid];
  for (int idx = tid; idx < 71 * 10; idx += 512) ((float*)avT)[idx] = 0.f;
  if (tid < 128) {
    int r = tid >> 4, d4 = (tid & 15) << 2;
    float4 qv = *(const float4*)(q + ((size_t)n * 512 + i0 + r) * 64 + d4);
    float4 bv = *(const float4*)(bh + d4);
    *(float4*)(&qs[r][d4]) =
        make_float4(qv.x + bv.x, qv.y + bv.y, qv.z + bv.z, qv.w + bv.w);
  }
  for (int idx = tid; idx < 71 * 16; idx += 512) {
    int row = idx >> 4, d4 = (idx & 15) << 2;
    int j = jlo0 + row;
    float4 v = make_float4(0.f, 0.f, 0.f, 0.f);
    if (j >= 0 && j < 512)
      v = *(const float4*)(k + ((size_t)n * 512 + j) * 64 + d4);
    *(float4*)(&ks[row][d4]) = v;
  }
  __syncthreads();

  // ---- Phase A2: scores + softmax + a-write. Wave w -> row w ----
  {
    int r = w;
    int i = i0 + r;
    int j = jlo0 + r + lane;
    bool valid = (j >= 0 && j < 512);
    const float* krow = &ks[r + lane][0];  // stride 68: conflict-free f4
    float e = 0.f;
#pragma unroll
    for (int d4 = 0; d4 < 64; d4 += 4) {
      float4 kv = *(const float4*)(krow + d4);
      float4 qv = *(const float4*)(&qs[r][d4]);
      float4 wv = *(const float4*)(&was[d4]);
      float h0 = qv.x + kv.x, h1 = qv.y + kv.y;
      float h2 = qv.z + kv.z, h3 = qv.w + kv.w;
      float t0 = 1.f - 2.f * __builtin_amdgcn_rcpf(__expf(2.f * h0) + 1.f);
      float t1 = 1.f - 2.f * __builtin_amdgcn_rcpf(__expf(2.f * h1) + 1.f);
      float t2 = 1.f - 2.f * __builtin_amdgcn_rcpf(__expf(2.f * h2) + 1.f);
      float t3 = 1.f - 2.f * __builtin_amdgcn_rcpf(__expf(2.f * h3) + 1.f);
      e += wv.x * t0 + wv.y * t1 + wv.z * t2 + wv.w * t3;
    }
    e += ba[0];
    if (!valid) e = -1e30f;

    float m = e;
    for (int o = 32; o > 0; o >>= 1) m = fmaxf(m, __shfl_xor(m, o, 64));
    float ex = valid ? __expf(e - m) : 0.f;
    float s = ex;
    for (int o = 32; o > 0; o >>= 1) s += __shfl_xor(s, o, 64);
    float aw = ex / (s + 1e-6f);
    avT[r + lane][r] = aw;  // abs col = r + lane

    float* arow = a + ((size_t)n * 512 + i) * 512;
    int jlo = i - 32;
#pragma unroll
    for (int t = 0; t < 2; t++) {
      int col0 = 4 * lane + 256 * t;
      float4 v;
      { int jr = col0 + 0 - jlo; int jc = min(max(jr, 0), 63); v.x = (jr >= 0 && jr < 64) ? avT[r + jc][r] : 0.f; }
      { int jr = col0 + 1 - jlo; int jc = min(max(jr, 0), 63); v.y = (jr >= 0 && jr < 64) ? avT[r + jc][r] : 0.f; }
      { int jr = col0 + 2 - jlo; int jc = min(max(jr, 0), 63); v.z = (jr >= 0 && jr < 64) ? avT[r + jc][r] : 0.f; }
      { int jr = col0 + 3 - jlo; int jc = min(max(jr, 0), 63); v.w = (jr >= 0 && jr < 64) ? avT[r + jc][r] : 0.f; }
      *(float4*)(arow + col0) = v;
    }
  }
  __syncthreads();

  // ---- Phase B: v = a@xt + residual -> xstT[c][r] ----
  {
    int c = tid & 127;
    int rh = tid >> 7;  // 0..3 -> rows 2rh, 2rh+1
    int r0 = 2 * rh;
    const float* xtn = xt + (size_t)n * 512 * 128;
    float acc0 = 0.f, acc1 = 0.f;
    for (int col = r0; col <= r0 + 64; col++) {  // 65 cols, avT=0 off-band
      int jj = jlo0 + col;
      int jc = min(max(jj, 0), 511);
      float xv = xtn[(size_t)jc * 128 + c];
      float2 av2 = *(const float2*)(&avT[col][r0]);  // broadcast b64
      acc0 += av2.x * xv;
      acc1 += av2.y * xv;
    }
    float res0 = xtn[(size_t)(i0 + r0) * 128 + c];
    float res1 = xtn[(size_t)(i0 + r0 + 1) * 128 + c];
    *(float2*)(&xstT[c][r0]) = make_float2(acc0 + res0, acc1 + res1);
  }
  __syncthreads();

  // ---- Phase B2: LN0 in place on xstT. Wave w -> row w ----
  {
    float a0 = xstT[lane][w], a1 = xstT[lane + 64][w];
    float s = a0 + a1, s2 = a0 * a0 + a1 * a1;
    for (int o = 32; o > 0; o >>= 1) {
      s += __shfl_xor(s, o, 64);
      s2 += __shfl_xor(s2, o, 64);
    }
    float mu = s * (1.f / 128.f);
    float var = s2 * (1.f / 128.f) - mu * mu;
    float rs = rsqrtf(var + 1e-5f);
    xstT[lane][w] = (a0 - mu) * rs * g0[lane] + be0[lane];
    xstT[lane + 64][w] = (a1 - mu) * rs * g0[lane + 64] + be0[lane + 64];
  }
  __syncthreads();

  // ---- Phase C: GEMM1 (in-wave 4-way K-split) + bias + relu -> tstT ----
  {
    int g = lane & 15;   // f4-group within wave
    int kq = lane >> 4;  // K-quarter 0..3
    int f0 = (16 * w + g) << 2;
    float acc[8][4];
#pragma unroll
    for (int i = 0; i < 8; i++)
#pragma unroll
      for (int u = 0; u < 4; u++) acc[i][u] = 0.f;
    int ccb = kq << 5;
#pragma unroll 4
    for (int cc = ccb; cc < ccb + 32; cc++) {
      float4 xa = *(const float4*)(&xstT[cc][0]);  // rows 0..3 (bcast x4 grp)
      float4 xb = *(const float4*)(&xstT[cc][4]);  // rows 4..7
      float4 wv = *(const float4*)(W0 + (size_t)cc * 512 + f0);
      acc[0][0] += xa.x * wv.x; acc[0][1] += xa.x * wv.y; acc[0][2] += xa.x * wv.z; acc[0][3] += xa.x * wv.w;
      acc[1][0] += xa.y * wv.x; acc[1][1] += xa.y * wv.y; acc[1][2] += xa.y * wv.z; acc[1][3] += xa.y * wv.w;
      acc[2][0] += xa.z * wv.x; acc[2][1] += xa.z * wv.y; acc[2][2] += xa.z * wv.z; acc[2][3] += xa.z * wv.w;
      acc[3][0] += xa.w * wv.x; acc[3][1] += xa.w * wv.y; acc[3][2] += xa.w * wv.z; acc[3][3] += xa.w * wv.w;
      acc[4][0] += xb.x * wv.x; acc[4][1] += xb.x * wv.y; acc[4][2] += xb.x * wv.z; acc[4][3] += xb.x * wv.w;
      acc[5][0] += xb.y * wv.x; acc[5][1] += xb.y * wv.y; acc[5][2] += xb.y * wv.z; acc[5][3] += xb.y * wv.w;
      acc[6][0] += xb.z * wv.x; acc[6][1] += xb.z * wv.y; acc[6][2] += xb.z * wv.z; acc[6][3] += xb.z * wv.w;
      acc[7][0] += xb.w * wv.x; acc[7][1] += xb.w * wv.y; acc[7][2] += xb.w * wv.z; acc[7][3] += xb.w * wv.w;
    }
    // butterfly-reduce over kq (lane bits 4,5)
#pragma unroll
    for (int i = 0; i < 8; i++)
#pragma unroll
      for (int u = 0; u < 4; u++) {
        float v = acc[i][u];
        v += __shfl_xor(v, 16, 64);
        v += __shfl_xor(v, 32, 64);
        acc[i][u] = v;
      }
    // lane (g,kq) writes f = f0+kq, all 8 rows (compile-time idx + select)
    int f = f0 + kq;
    float bb = b0[f];
    float r0v[8];
#pragma unroll
    for (int i = 0; i < 8; i++) {
      float v = (kq == 0) ? acc[i][0] : (kq == 1) ? acc[i][1]
              : (kq == 2) ? acc[i][2] : acc[i][3];
      r0v[i] = fmaxf(v + bb, 0.f);
    }
    *(float4*)(&tstT[f][0]) = make_float4(r0v[0], r0v[1], r0v[2], r0v[3]);
    *(float4*)(&tstT[f][4]) = make_float4(r0v[4], r0v[5], r0v[6], r0v[7]);
  }
  __syncthreads();

  // ---- Phase C2: GEMM2. Wave w = K-octile; lane: 32 c-quads x 2 row-halves
  {
    int c0 = (lane & 31) << 2;
    int rh = lane >> 5;  // 0..1 -> rows 4rh..4rh+3
    float acc[4][4];
#pragma unroll
    for (int i = 0; i < 4; i++)
#pragma unroll
      for (int u = 0; u < 4; u++) acc[i][u] = 0.f;
    const float* W1p = W1 + (size_t)w * 64 * 128;
    int tb = w << 6;
#pragma unroll 4
    for (int t = 0; t < 64; t++) {
      float4 tv = *(const float4*)(&tstT[tb + t][4 * rh]);  // 2-addr bcast
      float4 wv = *(const float4*)(W1p + (size_t)t * 128 + c0);
      acc[0][0] += tv.x * wv.x; acc[0][1] += tv.x * wv.y; acc[0][2] += tv.x * wv.z; acc[0][3] += tv.x * wv.w;
      acc[1][0] += tv.y * wv.x; acc[1][1] += tv.y * wv.y; acc[1][2] += tv.y * wv.z; acc[1][3] += tv.y * wv.w;
      acc[2][0] += tv.z * wv.x; acc[2][1] += tv.z * wv.y; acc[2][2] += tv.z * wv.z; acc[2][3] += tv.z * wv.w;
      acc[3][0] += tv.w * wv.x; acc[3][1] += tv.w * wv.y; acc[3][2] += tv.w * wv.z; acc[3][3] += tv.w * wv.w;
    }
#pragma unroll
    for (int i = 0; i < 4; i++) {
      *(float4*)(&part[w][4 * rh + i][c0]) =
          make_float4(acc[i][0], acc[i][1], acc[i][2], acc[i][3]);
    }
  }
  __syncthreads();

  // ---- combine partials + bias + residual -> ys ----
  if (tid < 256) {
    int r = tid >> 5, c0 = (tid & 31) << 2;
    float4 s = make_float4(0.f, 0.f, 0.f, 0.f);
#pragma unroll
    for (int ko = 0; ko < 8; ko++) {
      float4 p = *(const float4*)(&part[ko][r][c0]);
      s.x += p.x; s.y += p.y; s.z += p.z; s.w += p.w;
    }
    float4 bv = *(const float4*)(b1 + c0);
    s.x += bv.x + xstT[c0 + 0][r];
    s.y += bv.y + xstT[c0 + 1][r];
    s.z += bv.z + xstT[c0 + 2][r];
    s.w += bv.w + xstT[c0 + 3][r];
    *(float4*)(&ys[r][c0]) = s;
  }
  __syncthreads();

  // ---- LN1: wave w -> row w ----
  {
    float a0 = ys[w][lane], a1 = ys[w][lane + 64];
    float s = a0 + a1, s2 = a0 * a0 + a1 * a1;
    for (int o = 32; o > 0; o >>= 1) {
      s += __shfl_xor(s, o, 64);
      s2 += __shfl_xor(s2, o, 64);
    }
    float mu = s * (1.f / 128.f);
    float var = s2 * (1.f / 128.f) - mu * mu;
    float rs = rsqrtf(var + 1e-5f);
    ys[w][lane] = (a0 - mu) * rs * g1[lane] + be1[lane];
    ys[w][lane + 64] = (a1 - mu) * rs * g1[lane + 64] + be1[lane + 64];
  }
  __syncthreads();

  // ---- transposed write: out (N,C,L); 8 consecutive l per c ----
  {
    int c = tid >> 2, tq = tid & 3;
    *(float2*)(out + ((size_t)n * 128 + c) * 512 + i0 + 2 * tq) =
        make_float2(ys[2 * tq][c], ys[2 * tq + 1][c]);
  }
}

// ---------------------------------------------------------------------------
extern "C" void kernel_launch(void* const* d_in, const int* in_sizes, int n_in,
                              void* d_out, int out_size, void* d_ws, size_t ws_size,
                              hipStream_t stream) {
  const float* x   = (const float*)d_in[0];
  const float* Wx  = (const float*)d_in[1];
  const float* Wt  = (const float*)d_in[2];
  const float* bh  = (const float*)d_in[3];
  const float* Wa  = (const float*)d_in[4];
  const float* ba  = (const float*)d_in[5];
  const float* W0  = (const float*)d_in[6];
  const float* b0  = (const float*)d_in[7];
  const float* W1  = (const float*)d_in[8];
  const float* b1  = (const float*)d_in[9];
  const float* g0  = (const float*)d_in[10];
  const float* be0 = (const float*)d_in[11];
  const float* g1  = (const float*)d_in[12];
  const float* be1 = (const float*)d_in[13];

  float* outx = (float*)d_out;           // N*C*L = 524288
  float* outa = outx + (size_t)524288;   // N*L*L = 2097152

  float* ws = (float*)d_ws;
  float* xt = ws;              // 524288
  float* q  = xt + 524288;     // 262144
  float* k  = q + 262144;      // 262144

  prep_kernel<<<512, 256, 0, stream>>>(x, Wt, Wx, xt, q, k);
  attn_ffn_fused_kernel<<<512, 512, 0, stream>>>(
      q, k, bh, Wa, ba, xt, g0, be0, W0, b0, W1, b1, g1, be1, outa, outx);
}

// Round 4
// 124.729 us; speedup vs baseline: 1.1270x; 1.0013x over previous
//
#include <hip/hip_runtime.h>
#include <cstddef>

// N=8, C=128, L=512, D=64, F=512, ATTN_W=64

// ---------------------------------------------------------------------------
// Kernel 1: prep = q/k projection only (xt eliminated). grid 256, block 512.
// Block = (n, l-tile of 16). Half 0 (tid<256): q via Wt; half 1: k via Wx.
// ---------------------------------------------------------------------------
__global__ __launch_bounds__(512) void prep_kernel(
    const float* __restrict__ x, const float* __restrict__ Wt,
    const float* __restrict__ Wx, float* __restrict__ q,
    float* __restrict__ k) {
  __shared__ float xs[128][17];
  int tid = threadIdx.x;
  int n = blockIdx.x >> 5;
  int l0 = (blockIdx.x & 31) << 4;

  {  // stage x tile: 128 c x 16 l  (512 float4 tasks, one per thread)
    int c = tid >> 2, v = tid & 3;
    float4 d4 = *(const float4*)(x + ((size_t)n * 128 + c) * 512 + l0 + 4 * v);
    xs[c][4 * v + 0] = d4.x; xs[c][4 * v + 1] = d4.y;
    xs[c][4 * v + 2] = d4.z; xs[c][4 * v + 3] = d4.w;
  }
  __syncthreads();

  int half = tid >> 8;       // 0: q/Wt, 1: k/Wx
  int t = tid & 255;
  int r = t >> 4;            // 0..15
  int f0 = (t & 15) << 2;    // 0..60
  const float* W = half ? Wx : Wt;
  float* dst = half ? k : q;
  float acc[4] = {0.f, 0.f, 0.f, 0.f};
#pragma unroll 4
  for (int cc = 0; cc < 128; cc++) {
    float xv = xs[cc][r];
    float4 w = *(const float4*)(W + cc * 64 + f0);
    acc[0] += xv * w.x; acc[1] += xv * w.y;
    acc[2] += xv * w.z; acc[3] += xv * w.w;
  }
  *(float4*)(dst + ((size_t)n * 512 + l0 + r) * 64 + f0) =
      make_float4(acc[0], acc[1], acc[2], acc[3]);
}

// ---------------------------------------------------------------------------
// Kernel 2: FUSED attn+FFN. 8 rows/block, grid 512, block 512 (8 waves),
// 2 blocks/CU. x-window staged directly from x (no xt round-trip).
// GEMM1/GEMM2: fully-unrolled outer loops with 4-deep register weight
// prefetch (loads issue one FMA-block ahead of use).
// ---------------------------------------------------------------------------
__global__ __launch_bounds__(512, 4) void attn_ffn_fused_kernel(
    const float* __restrict__ x, const float* __restrict__ q,
    const float* __restrict__ k, const float* __restrict__ bh,
    const float* __restrict__ Wa, const float* __restrict__ ba,
    const float* __restrict__ g0, const float* __restrict__ be0,
    const float* __restrict__ W0, const float* __restrict__ b0,
    const float* __restrict__ W1, const float* __restrict__ b1,
    const float* __restrict__ g1, const float* __restrict__ be1,
    float* __restrict__ a, float* __restrict__ out) {
  // Aliased region (61440 B):
  //  Phases A/B: ks[71][68] @0 (19312), qs[8][64] @19312 (2048),
  //              xtw[72][132] @21360 (38016) -> 59376 B
  //  Phases C+:  tstT[512][12] @0 (24576), part[8][8][128] @24576 (32768),
  //              ys[8][128] @57344 (4096) -> 61440 B
  __shared__ __align__(16) char smem[61440];
  __shared__ __align__(16) float xstT[128][12];  // x2 tile [c][r]
  __shared__ __align__(16) float avT[71][10];    // [abs_col][row], skewed
  __shared__ __align__(16) float was[64];

  float (*ks)[68] = (float(*)[68])smem;              // [71][68]
  float (*qs)[64] = (float(*)[64])(smem + 19312);    // [8][64]
  float (*xtw)[132] = (float(*)[132])(smem + 21360); // [72][132]
  float (*tstT)[12] = (float(*)[12])smem;            // [512][12]
  float (*part)[8][128] = (float(*)[8][128])(smem + 24576);  // [8][8][128]
  float (*ys)[128] = (float(*)[128])(smem + 57344);          // [8][128]

  int tid = threadIdx.x;
  int w = tid >> 6, lane = tid & 63;
  size_t rbase = (size_t)blockIdx.x * 8;
  int n = (int)(rbase >> 9);
  int i0 = (int)(rbase & 511);
  int jlo0 = i0 - 32;

  // ---- Phase A: stage q(+bh), k-window, x-window; zero avT ----
  if (tid < 64) was[tid] = Wa[tid];
  for (int idx = tid; idx < 71 * 10; idx += 512) ((float*)avT)[idx] = 0.f;
  if (tid < 128) {
    int r = tid >> 4, d4 = (tid & 15) << 2;
    float4 qv = *(const float4*)(q + ((size_t)n * 512 + i0 + r) * 64 + d4);
    float4 bv = *(const float4*)(bh + d4);
    *(float4*)(&qs[r][d4]) =
        make_float4(qv.x + bv.x, qv.y + bv.y, qv.z + bv.z, qv.w + bv.w);
  }
  for (int idx = tid; idx < 71 * 16; idx += 512) {
    int row = idx >> 4, d4 = (idx & 15) << 2;
    int j = jlo0 + row;
    float4 v = make_float4(0.f, 0.f, 0.f, 0.f);
    if (j >= 0 && j < 512)
      v = *(const float4*)(k + ((size_t)n * 512 + j) * 64 + d4);
    *(float4*)(&ks[row][d4]) = v;
  }
  // x-window: 128 c x 18 float4-chunks of l (72 rows; row 71 unused)
  for (int t = tid; t < 128 * 18; t += 512) {
    int c = t / 18;
    int u = t - c * 18;
    int row = 4 * u;
    int j0 = jlo0 + row;
    const float* xp = x + ((size_t)n * 128 + c) * 512;
    float4 v = make_float4(0.f, 0.f, 0.f, 0.f);
    if (j0 >= 0 && j0 + 3 < 512) {
      v = *(const float4*)(xp + j0);
    } else {
      if (j0 + 0 >= 0 && j0 + 0 < 512) v.x = xp[j0 + 0];
      if (j0 + 1 >= 0 && j0 + 1 < 512) v.y = xp[j0 + 1];
      if (j0 + 2 >= 0 && j0 + 2 < 512) v.z = xp[j0 + 2];
      if (j0 + 3 >= 0 && j0 + 3 < 512) v.w = xp[j0 + 3];
    }
    xtw[row + 0][c] = v.x; xtw[row + 1][c] = v.y;
    xtw[row + 2][c] = v.z; xtw[row + 3][c] = v.w;
  }
  __syncthreads();

  // ---- Phase A2: scores + softmax + a-write. Wave w -> row w ----
  {
    int r = w;
    int i = i0 + r;
    int j = jlo0 + r + lane;
    bool valid = (j >= 0 && j < 512);
    const float* krow = &ks[r + lane][0];  // stride 68: conflict-free f4
    float e = 0.f;
#pragma unroll
    for (int d4 = 0; d4 < 64; d4 += 4) {
      float4 kv = *(const float4*)(krow + d4);
      float4 qv = *(const float4*)(&qs[r][d4]);
      float4 wv = *(const float4*)(&was[d4]);
      float h0 = qv.x + kv.x, h1 = qv.y + kv.y;
      float h2 = qv.z + kv.z, h3 = qv.w + kv.w;
      float t0 = 1.f - 2.f * __builtin_amdgcn_rcpf(__expf(2.f * h0) + 1.f);
      float t1 = 1.f - 2.f * __builtin_amdgcn_rcpf(__expf(2.f * h1) + 1.f);
      float t2 = 1.f - 2.f * __builtin_amdgcn_rcpf(__expf(2.f * h2) + 1.f);
      float t3 = 1.f - 2.f * __builtin_amdgcn_rcpf(__expf(2.f * h3) + 1.f);
      e += wv.x * t0 + wv.y * t1 + wv.z * t2 + wv.w * t3;
    }
    e += ba[0];
    if (!valid) e = -1e30f;

    float m = e;
    for (int o = 32; o > 0; o >>= 1) m = fmaxf(m, __shfl_xor(m, o, 64));
    float ex = valid ? __expf(e - m) : 0.f;
    float s = ex;
    for (int o = 32; o > 0; o >>= 1) s += __shfl_xor(s, o, 64);
    avT[r + lane][r] = ex / (s + 1e-6f);  // abs col = r + lane

    float* arow = a + ((size_t)n * 512 + i) * 512;
    int jlo = i - 32;
#pragma unroll
    for (int t = 0; t < 2; t++) {
      int col0 = 4 * lane + 256 * t;
      float4 v;
      { int jr = col0 + 0 - jlo; int jc = min(max(jr, 0), 63); v.x = (jr >= 0 && jr < 64) ? avT[r + jc][r] : 0.f; }
      { int jr = col0 + 1 - jlo; int jc = min(max(jr, 0), 63); v.y = (jr >= 0 && jr < 64) ? avT[r + jc][r] : 0.f; }
      { int jr = col0 + 2 - jlo; int jc = min(max(jr, 0), 63); v.z = (jr >= 0 && jr < 64) ? avT[r + jc][r] : 0.f; }
      { int jr = col0 + 3 - jlo; int jc = min(max(jr, 0), 63); v.w = (jr >= 0 && jr < 64) ? avT[r + jc][r] : 0.f; }
      *(float4*)(arow + col0) = v;
    }
  }
  __syncthreads();

  // ---- Phase B: v = a@x + residual -> xstT[c][r] (all-LDS) ----
  {
    int c = tid & 127;
    int r0 = (tid >> 7) << 1;  // 0,2,4,6 -> rows r0, r0+1
    float acc0 = 0.f, acc1 = 0.f;
#pragma unroll 5
    for (int m = 0; m < 65; m++) {
      int col = r0 + m;
      float xv = xtw[col][c];                        // b32 conflict-free
      float2 av2 = *(const float2*)(&avT[col][r0]);  // broadcast b64
      acc0 += av2.x * xv;
      acc1 += av2.y * xv;
    }
    float res0 = xtw[32 + r0][c];
    float res1 = xtw[33 + r0][c];
    *(float2*)(&xstT[c][r0]) = make_float2(acc0 + res0, acc1 + res1);
  }
  __syncthreads();

  // ---- Phase B2: LN0 in place on xstT. Wave w -> row w ----
  {
    float a0 = xstT[lane][w], a1 = xstT[lane + 64][w];
    float s = a0 + a1, s2 = a0 * a0 + a1 * a1;
    for (int o = 32; o > 0; o >>= 1) {
      s += __shfl_xor(s, o, 64);
      s2 += __shfl_xor(s2, o, 64);
    }
    float mu = s * (1.f / 128.f);
    float var = s2 * (1.f / 128.f) - mu * mu;
    float rs = rsqrtf(var + 1e-5f);
    xstT[lane][w] = (a0 - mu) * rs * g0[lane] + be0[lane];
    xstT[lane + 64][w] = (a1 - mu) * rs * g0[lane + 64] + be0[lane + 64];
  }
  __syncthreads();

  // ---- Phase C: GEMM1 (in-wave 4-way K-split, 4-deep W prefetch) ----
  {
    int g = lane & 15;   // f4-group within wave
    int kq = lane >> 4;  // K-quarter 0..3
    int f0 = (16 * w + g) << 2;
    int ccb = kq << 5;
    const float* w0p = W0 + (size_t)ccb * 512 + f0;
    float acc[8][4];
#pragma unroll
    for (int i = 0; i < 8; i++)
#pragma unroll
      for (int u = 0; u < 4; u++) acc[i][u] = 0.f;

    float4 wbuf[4];
#pragma unroll
    for (int p = 0; p < 4; p++)
      wbuf[p] = *(const float4*)(w0p + (size_t)p * 512);
#pragma unroll
    for (int c4 = 0; c4 < 8; c4++) {
      float4 cur0 = wbuf[0], cur1 = wbuf[1], cur2 = wbuf[2], cur3 = wbuf[3];
      if (c4 < 7) {
#pragma unroll
        for (int p = 0; p < 4; p++)
          wbuf[p] = *(const float4*)(w0p + (size_t)((c4 + 1) * 4 + p) * 512);
      }
#pragma unroll
      for (int p = 0; p < 4; p++) {
        int cc = ccb + c4 * 4 + p;
        float4 wv = (p == 0) ? cur0 : (p == 1) ? cur1 : (p == 2) ? cur2 : cur3;
        float4 xa = *(const float4*)(&xstT[cc][0]);  // broadcast
        float4 xb = *(const float4*)(&xstT[cc][4]);
        acc[0][0] += xa.x * wv.x; acc[0][1] += xa.x * wv.y; acc[0][2] += xa.x * wv.z; acc[0][3] += xa.x * wv.w;
        acc[1][0] += xa.y * wv.x; acc[1][1] += xa.y * wv.y; acc[1][2] += xa.y * wv.z; acc[1][3] += xa.y * wv.w;
        acc[2][0] += xa.z * wv.x; acc[2][1] += xa.z * wv.y; acc[2][2] += xa.z * wv.z; acc[2][3] += xa.z * wv.w;
        acc[3][0] += xa.w * wv.x; acc[3][1] += xa.w * wv.y; acc[3][2] += xa.w * wv.z; acc[3][3] += xa.w * wv.w;
        acc[4][0] += xb.x * wv.x; acc[4][1] += xb.x * wv.y; acc[4][2] += xb.x * wv.z; acc[4][3] += xb.x * wv.w;
        acc[5][0] += xb.y * wv.x; acc[5][1] += xb.y * wv.y; acc[5][2] += xb.y * wv.z; acc[5][3] += xb.y * wv.w;
        acc[6][0] += xb.z * wv.x; acc[6][1] += xb.z * wv.y; acc[6][2] += xb.z * wv.z; acc[6][3] += xb.z * wv.w;
        acc[7][0] += xb.w * wv.x; acc[7][1] += xb.w * wv.y; acc[7][2] += xb.w * wv.z; acc[7][3] += xb.w * wv.w;
      }
    }
    // butterfly-reduce over kq (lane bits 4,5)
#pragma unroll
    for (int i = 0; i < 8; i++)
#pragma unroll
      for (int u = 0; u < 4; u++) {
        float v = acc[i][u];
        v += __shfl_xor(v, 16, 64);
        v += __shfl_xor(v, 32, 64);
        acc[i][u] = v;
      }
    int f = f0 + kq;
    float bb = b0[f];
    float r0v[8];
#pragma unroll
    for (int i = 0; i < 8; i++) {
      float v = (kq == 0) ? acc[i][0] : (kq == 1) ? acc[i][1]
              : (kq == 2) ? acc[i][2] : acc[i][3];
      r0v[i] = fmaxf(v + bb, 0.f);
    }
    *(float4*)(&tstT[f][0]) = make_float4(r0v[0], r0v[1], r0v[2], r0v[3]);
    *(float4*)(&tstT[f][4]) = make_float4(r0v[4], r0v[5], r0v[6], r0v[7]);
  }
  __syncthreads();

  // ---- Phase C2: GEMM2 (wave = K-octile, 4-deep W prefetch) -> part ----
  {
    int c0 = (lane & 31) << 2;
    int rh = lane >> 5;  // 0..1 -> rows 4rh..4rh+3
    const float* W1p = W1 + (size_t)w * 64 * 128 + c0;
    int tb = w << 6;
    float acc[4][4];
#pragma unroll
    for (int i = 0; i < 4; i++)
#pragma unroll
      for (int u = 0; u < 4; u++) acc[i][u] = 0.f;

    float4 wbuf[4];
#pragma unroll
    for (int p = 0; p < 4; p++)
      wbuf[p] = *(const float4*)(W1p + (size_t)p * 128);
#pragma unroll
    for (int t4 = 0; t4 < 16; t4++) {
      float4 cur0 = wbuf[0], cur1 = wbuf[1], cur2 = wbuf[2], cur3 = wbuf[3];
      if (t4 < 15) {
#pragma unroll
        for (int p = 0; p < 4; p++)
          wbuf[p] = *(const float4*)(W1p + (size_t)((t4 + 1) * 4 + p) * 128);
      }
#pragma unroll
      for (int p = 0; p < 4; p++) {
        int t = t4 * 4 + p;
        float4 wv = (p == 0) ? cur0 : (p == 1) ? cur1 : (p == 2) ? cur2 : cur3;
        float4 tv = *(const float4*)(&tstT[tb + t][4 * rh]);  // 2-addr bcast
        acc[0][0] += tv.x * wv.x; acc[0][1] += tv.x * wv.y; acc[0][2] += tv.x * wv.z; acc[0][3] += tv.x * wv.w;
        acc[1][0] += tv.y * wv.x; acc[1][1] += tv.y * wv.y; acc[1][2] += tv.y * wv.z; acc[1][3] += tv.y * wv.w;
        acc[2][0] += tv.z * wv.x; acc[2][1] += tv.z * wv.y; acc[2][2] += tv.z * wv.z; acc[2][3] += tv.z * wv.w;
        acc[3][0] += tv.w * wv.x; acc[3][1] += tv.w * wv.y; acc[3][2] += tv.w * wv.z; acc[3][3] += tv.w * wv.w;
      }
    }
#pragma unroll
    for (int i = 0; i < 4; i++) {
      *(float4*)(&part[w][4 * rh + i][c0]) =
          make_float4(acc[i][0], acc[i][1], acc[i][2], acc[i][3]);
    }
  }
  __syncthreads();

  // ---- merged combine + bias + residual + LN1. Wave w -> row w ----
  {
    float a0 = b1[lane] + xstT[lane][w];
    float a1 = b1[lane + 64] + xstT[lane + 64][w];
#pragma unroll
    for (int ko = 0; ko < 8; ko++) {
      a0 += part[ko][w][lane];        // conflict-free b32
      a1 += part[ko][w][lane + 64];
    }
    float s = a0 + a1, s2 = a0 * a0 + a1 * a1;
    for (int o = 32; o > 0; o >>= 1) {
      s += __shfl_xor(s, o, 64);
      s2 += __shfl_xor(s2, o, 64);
    }
    float mu = s * (1.f / 128.f);
    float var = s2 * (1.f / 128.f) - mu * mu;
    float rs = rsqrtf(var + 1e-5f);
    ys[w][lane] = (a0 - mu) * rs * g1[lane] + be1[lane];
    ys[w][lane + 64] = (a1 - mu) * rs * g1[lane + 64] + be1[lane + 64];
  }
  __syncthreads();

  // ---- transposed write: out (N,C,L); 8 consecutive l per c ----
  {
    int c = tid >> 2, tq = tid & 3;
    *(float2*)(out + ((size_t)n * 128 + c) * 512 + i0 + 2 * tq) =
        make_float2(ys[2 * tq][c], ys[2 * tq + 1][c]);
  }
}

// ---------------------------------------------------------------------------
extern "C" void kernel_launch(void* const* d_in, const int* in_sizes, int n_in,
                              void* d_out, int out_size, void* d_ws, size_t ws_size,
                              hipStream_t stream) {
  const float* x   = (const float*)d_in[0];
  const float* Wx  = (const float*)d_in[1];
  const float* Wt  = (const float*)d_in[2];
  const float* bh  = (const float*)d_in[3];
  const float* Wa  = (const float*)d_in[4];
  const float* ba  = (const float*)d_in[5];
  const float* W0  = (const float*)d_in[6];
  const float* b0  = (const float*)d_in[7];
  const float* W1  = (const float*)d_in[8];
  const float* b1  = (const float*)d_in[9];
  const float* g0  = (const float*)d_in[10];
  const float* be0 = (const float*)d_in[11];
  const float* g1  = (const float*)d_in[12];
  const float* be1 = (const float*)d_in[13];

  float* outx = (float*)d_out;           // N*C*L = 524288
  float* outa = outx + (size_t)524288;   // N*L*L = 2097152

  float* ws = (float*)d_ws;
  float* q  = ws;              // 262144
  float* k  = q + 262144;      // 262144

  prep_kernel<<<256, 512, 0, stream>>>(x, Wt, Wx, q, k);
  attn_ffn_fused_kernel<<<512, 512, 0, stream>>>(
      x, q, k, bh, Wa, ba, g0, be0, W0, b0, W1, b1, g1, be1, outa, outx);
}

// Round 5
// 124.638 us; speedup vs baseline: 1.1279x; 1.0007x over previous
//
#include <hip/hip_runtime.h>
#include <cstddef>

// N=8, C=128, L=512, D=64, F=512, ATTN_W=64

// ---------------------------------------------------------------------------
// Kernel 1: prep = q/k projection only. grid 256, block 512.
// Block = (n, l-tile of 16). Half 0 (tid<256): q via Wt; half 1: k via Wx.
// ---------------------------------------------------------------------------
__global__ __launch_bounds__(512) void prep_kernel(
    const float* __restrict__ x, const float* __restrict__ Wt,
    const float* __restrict__ Wx, float* __restrict__ q,
    float* __restrict__ k) {
  __shared__ float xs[128][17];
  int tid = threadIdx.x;
  int n = blockIdx.x >> 5;
  int l0 = (blockIdx.x & 31) << 4;

  {  // stage x tile: 128 c x 16 l  (512 float4 tasks, one per thread)
    int c = tid >> 2, v = tid & 3;
    float4 d4 = *(const float4*)(x + ((size_t)n * 128 + c) * 512 + l0 + 4 * v);
    xs[c][4 * v + 0] = d4.x; xs[c][4 * v + 1] = d4.y;
    xs[c][4 * v + 2] = d4.z; xs[c][4 * v + 3] = d4.w;
  }
  __syncthreads();

  int half = tid >> 8;       // 0: q/Wt, 1: k/Wx
  int t = tid & 255;
  int r = t >> 4;            // 0..15
  int f0 = (t & 15) << 2;    // 0..60
  const float* W = half ? Wx : Wt;
  float* dst = half ? k : q;
  float acc[4] = {0.f, 0.f, 0.f, 0.f};
#pragma unroll 4
  for (int cc = 0; cc < 128; cc++) {
    float xv = xs[cc][r];
    float4 w = *(const float4*)(W + cc * 64 + f0);
    acc[0] += xv * w.x; acc[1] += xv * w.y;
    acc[2] += xv * w.z; acc[3] += xv * w.w;
  }
  *(float4*)(dst + ((size_t)n * 512 + l0 + r) * 64 + f0) =
      make_float4(acc[0], acc[1], acc[2], acc[3]);
}

// ---------------------------------------------------------------------------
// Kernel 2: FUSED attn+FFN. 8 rows/block, grid 512, block 512 (8 waves),
// 2 blocks/CU. XCD-swizzled tiles: XCD x owns 64 consecutive row-tiles so
// its private L2 caches the x/k/q slice (9x halo reuse becomes L2 hits).
// xtw natural layout [c][col], odd stride 77: staging writes lane-sequential,
// phase-B per-lane reads bank=(13c)%32 -> exact 2-way (free).
// ---------------------------------------------------------------------------
__global__ __launch_bounds__(512, 4) void attn_ffn_fused_kernel(
    const float* __restrict__ x, const float* __restrict__ q,
    const float* __restrict__ k, const float* __restrict__ bh,
    const float* __restrict__ Wa, const float* __restrict__ ba,
    const float* __restrict__ g0, const float* __restrict__ be0,
    const float* __restrict__ W0, const float* __restrict__ b0,
    const float* __restrict__ W1, const float* __restrict__ b1,
    const float* __restrict__ g1, const float* __restrict__ be1,
    float* __restrict__ a, float* __restrict__ out) {
  // Aliased region (61440 B):
  //  Phases A/B: ks[71][68] @0 (19312), qs[8][64] @19312 (2048),
  //              xtw[128][77] @21360 (39424) -> 60784 B
  //  Phases C+:  tstT[512][12] @0 (24576), part[8][8][128] @24576 (32768),
  //              ys[8][128] @57344 (4096) -> 61440 B
  __shared__ __align__(16) char smem[61440];
  __shared__ __align__(16) float xstT[128][12];  // x2 tile [c][r]
  __shared__ __align__(16) float avT[71][10];    // [abs_col][row], skewed
  __shared__ __align__(16) float was[64];

  float (*ks)[68] = (float(*)[68])smem;              // [71][68]
  float (*qs)[64] = (float(*)[64])(smem + 19312);    // [8][64]
  float (*xtw)[77] = (float(*)[77])(smem + 21360);   // [128][77]
  float (*tstT)[12] = (float(*)[12])smem;            // [512][12]
  float (*part)[8][128] = (float(*)[8][128])(smem + 24576);  // [8][8][128]
  float (*ys)[128] = (float(*)[128])(smem + 57344);          // [8][128]

  int tid = threadIdx.x;
  int w = tid >> 6, lane = tid & 63;
  // XCD-aware bijective swizzle: dispatch b -> XCD b%8; give XCD its own
  // contiguous 64-tile chunk (gridDim 512 % 8 == 0).
  int bid = blockIdx.x;
  int tile = (bid & 7) * 64 + (bid >> 3);
  size_t rbase = (size_t)tile * 8;
  int n = (int)(rbase >> 9);
  int i0 = (int)(rbase & 511);
  int jlo0 = i0 - 32;

  // ---- Phase A: stage q(+bh), k-window, x-window; zero avT ----
  if (tid < 64) was[tid] = Wa[tid];
  for (int idx = tid; idx < 71 * 10; idx += 512) ((float*)avT)[idx] = 0.f;
  if (tid < 128) {
    int r = tid >> 4, d4 = (tid & 15) << 2;
    float4 qv = *(const float4*)(q + ((size_t)n * 512 + i0 + r) * 64 + d4);
    float4 bv = *(const float4*)(bh + d4);
    *(float4*)(&qs[r][d4]) =
        make_float4(qv.x + bv.x, qv.y + bv.y, qv.z + bv.z, qv.w + bv.w);
  }
  for (int idx = tid; idx < 71 * 16; idx += 512) {
    int row = idx >> 4, d4 = (idx & 15) << 2;
    int j = jlo0 + row;
    float4 v = make_float4(0.f, 0.f, 0.f, 0.f);
    if (j >= 0 && j < 512)
      v = *(const float4*)(k + ((size_t)n * 512 + j) * 64 + d4);
    *(float4*)(&ks[row][d4]) = v;
  }
  // x-window: [c][col] natural orientation, 18 f4-chunks of col per c.
  // Global reads coalesced in 288B runs; LDS writes lane-sequential cols.
  for (int t = tid; t < 128 * 18; t += 512) {
    int c = t / 18;
    int u = t - c * 18;
    int col = 4 * u;
    int j0 = jlo0 + col;
    const float* xp = x + ((size_t)n * 128 + c) * 512;
    float4 v = make_float4(0.f, 0.f, 0.f, 0.f);
    if (j0 >= 0 && j0 + 3 < 512) {
      v = *(const float4*)(xp + j0);
    } else {
      if (j0 + 0 >= 0 && j0 + 0 < 512) v.x = xp[j0 + 0];
      if (j0 + 1 >= 0 && j0 + 1 < 512) v.y = xp[j0 + 1];
      if (j0 + 2 >= 0 && j0 + 2 < 512) v.z = xp[j0 + 2];
      if (j0 + 3 >= 0 && j0 + 3 < 512) v.w = xp[j0 + 3];
    }
    xtw[c][col + 0] = v.x; xtw[c][col + 1] = v.y;
    xtw[c][col + 2] = v.z; xtw[c][col + 3] = v.w;
  }
  __syncthreads();

  // ---- Phase A2: scores + softmax + a-write. Wave w -> row w ----
  {
    int r = w;
    int i = i0 + r;
    int j = jlo0 + r + lane;
    bool valid = (j >= 0 && j < 512);
    const float* krow = &ks[r + lane][0];  // stride 68: conflict-free f4
    float e = 0.f;
#pragma unroll
    for (int d4 = 0; d4 < 64; d4 += 4) {
      float4 kv = *(const float4*)(krow + d4);
      float4 qv = *(const float4*)(&qs[r][d4]);
      float4 wv = *(const float4*)(&was[d4]);
      float h0 = qv.x + kv.x, h1 = qv.y + kv.y;
      float h2 = qv.z + kv.z, h3 = qv.w + kv.w;
      float t0 = 1.f - 2.f * __builtin_amdgcn_rcpf(__expf(2.f * h0) + 1.f);
      float t1 = 1.f - 2.f * __builtin_amdgcn_rcpf(__expf(2.f * h1) + 1.f);
      float t2 = 1.f - 2.f * __builtin_amdgcn_rcpf(__expf(2.f * h2) + 1.f);
      float t3 = 1.f - 2.f * __builtin_amdgcn_rcpf(__expf(2.f * h3) + 1.f);
      e += wv.x * t0 + wv.y * t1 + wv.z * t2 + wv.w * t3;
    }
    e += ba[0];
    if (!valid) e = -1e30f;

    float m = e;
    for (int o = 32; o > 0; o >>= 1) m = fmaxf(m, __shfl_xor(m, o, 64));
    float ex = valid ? __expf(e - m) : 0.f;
    float s = ex;
    for (int o = 32; o > 0; o >>= 1) s += __shfl_xor(s, o, 64);
    avT[r + lane][r] = ex / (s + 1e-6f);  // abs col = r + lane

    float* arow = a + ((size_t)n * 512 + i) * 512;
    int jlo = i - 32;
#pragma unroll
    for (int t = 0; t < 2; t++) {
      int col0 = 4 * lane + 256 * t;
      float4 v;
      { int jr = col0 + 0 - jlo; int jc = min(max(jr, 0), 63); v.x = (jr >= 0 && jr < 64) ? avT[r + jc][r] : 0.f; }
      { int jr = col0 + 1 - jlo; int jc = min(max(jr, 0), 63); v.y = (jr >= 0 && jr < 64) ? avT[r + jc][r] : 0.f; }
      { int jr = col0 + 2 - jlo; int jc = min(max(jr, 0), 63); v.z = (jr >= 0 && jr < 64) ? avT[r + jc][r] : 0.f; }
      { int jr = col0 + 3 - jlo; int jc = min(max(jr, 0), 63); v.w = (jr >= 0 && jr < 64) ? avT[r + jc][r] : 0.f; }
      *(float4*)(arow + col0) = v;
    }
  }
  __syncthreads();

  // ---- Phase B: v = a@x + residual -> xstT[c][r] (all-LDS) ----
  {
    int c = tid & 127;
    int r0 = (tid >> 7) << 1;  // 0,2,4,6 -> rows r0, r0+1
    const float* xr = &xtw[c][0];
    float acc0 = 0.f, acc1 = 0.f;
#pragma unroll 5
    for (int m = 0; m < 65; m++) {
      int col = r0 + m;
      float xv = xr[col];                            // b32, 2-way: free
      float2 av2 = *(const float2*)(&avT[col][r0]);  // broadcast b64
      acc0 += av2.x * xv;
      acc1 += av2.y * xv;
    }
    float res0 = xr[32 + r0];
    float res1 = xr[33 + r0];
    *(float2*)(&xstT[c][r0]) = make_float2(acc0 + res0, acc1 + res1);
  }
  __syncthreads();

  // ---- Phase B2: LN0 in place on xstT. Wave w -> row w ----
  {
    float a0 = xstT[lane][w], a1 = xstT[lane + 64][w];
    float s = a0 + a1, s2 = a0 * a0 + a1 * a1;
    for (int o = 32; o > 0; o >>= 1) {
      s += __shfl_xor(s, o, 64);
      s2 += __shfl_xor(s2, o, 64);
    }
    float mu = s * (1.f / 128.f);
    float var = s2 * (1.f / 128.f) - mu * mu;
    float rs = rsqrtf(var + 1e-5f);
    xstT[lane][w] = (a0 - mu) * rs * g0[lane] + be0[lane];
    xstT[lane + 64][w] = (a1 - mu) * rs * g0[lane + 64] + be0[lane + 64];
  }
  __syncthreads();

  // ---- Phase C: GEMM1 (in-wave 4-way K-split, 4-deep W prefetch) ----
  {
    int g = lane & 15;   // f4-group within wave
    int kq = lane >> 4;  // K-quarter 0..3
    int f0 = (16 * w + g) << 2;
    int ccb = kq << 5;
    const float* w0p = W0 + (size_t)ccb * 512 + f0;
    float acc[8][4];
#pragma unroll
    for (int i = 0; i < 8; i++)
#pragma unroll
      for (int u = 0; u < 4; u++) acc[i][u] = 0.f;

    float4 wbuf[4];
#pragma unroll
    for (int p = 0; p < 4; p++)
      wbuf[p] = *(const float4*)(w0p + (size_t)p * 512);
#pragma unroll
    for (int c4 = 0; c4 < 8; c4++) {
      float4 cur0 = wbuf[0], cur1 = wbuf[1], cur2 = wbuf[2], cur3 = wbuf[3];
      if (c4 < 7) {
#pragma unroll
        for (int p = 0; p < 4; p++)
          wbuf[p] = *(const float4*)(w0p + (size_t)((c4 + 1) * 4 + p) * 512);
      }
#pragma unroll
      for (int p = 0; p < 4; p++) {
        int cc = ccb + c4 * 4 + p;
        float4 wv = (p == 0) ? cur0 : (p == 1) ? cur1 : (p == 2) ? cur2 : cur3;
        float4 xa = *(const float4*)(&xstT[cc][0]);  // broadcast
        float4 xb = *(const float4*)(&xstT[cc][4]);
        acc[0][0] += xa.x * wv.x; acc[0][1] += xa.x * wv.y; acc[0][2] += xa.x * wv.z; acc[0][3] += xa.x * wv.w;
        acc[1][0] += xa.y * wv.x; acc[1][1] += xa.y * wv.y; acc[1][2] += xa.y * wv.z; acc[1][3] += xa.y * wv.w;
        acc[2][0] += xa.z * wv.x; acc[2][1] += xa.z * wv.y; acc[2][2] += xa.z * wv.z; acc[2][3] += xa.z * wv.w;
        acc[3][0] += xa.w * wv.x; acc[3][1] += xa.w * wv.y; acc[3][2] += xa.w * wv.z; acc[3][3] += xa.w * wv.w;
        acc[4][0] += xb.x * wv.x; acc[4][1] += xb.x * wv.y; acc[4][2] += xb.x * wv.z; acc[4][3] += xb.x * wv.w;
        acc[5][0] += xb.y * wv.x; acc[5][1] += xb.y * wv.y; acc[5][2] += xb.y * wv.z; acc[5][3] += xb.y * wv.w;
        acc[6][0] += xb.z * wv.x; acc[6][1] += xb.z * wv.y; acc[6][2] += xb.z * wv.z; acc[6][3] += xb.z * wv.w;
        acc[7][0] += xb.w * wv.x; acc[7][1] += xb.w * wv.y; acc[7][2] += xb.w * wv.z; acc[7][3] += xb.w * wv.w;
      }
    }
    // butterfly-reduce over kq (lane bits 4,5)
#pragma unroll
    for (int i = 0; i < 8; i++)
#pragma unroll
      for (int u = 0; u < 4; u++) {
        float v = acc[i][u];
        v += __shfl_xor(v, 16, 64);
        v += __shfl_xor(v, 32, 64);
        acc[i][u] = v;
      }
    int f = f0 + kq;
    float bb = b0[f];
    float r0v[8];
#pragma unroll
    for (int i = 0; i < 8; i++) {
      float v = (kq == 0) ? acc[i][0] : (kq == 1) ? acc[i][1]
              : (kq == 2) ? acc[i][2] : acc[i][3];
      r0v[i] = fmaxf(v + bb, 0.f);
    }
    *(float4*)(&tstT[f][0]) = make_float4(r0v[0], r0v[1], r0v[2], r0v[3]);
    *(float4*)(&tstT[f][4]) = make_float4(r0v[4], r0v[5], r0v[6], r0v[7]);
  }
  __syncthreads();

  // ---- Phase C2: GEMM2 (wave = K-octile, 4-deep W prefetch) -> part ----
  {
    int c0 = (lane & 31) << 2;
    int rh = lane >> 5;  // 0..1 -> rows 4rh..4rh+3
    const float* W1p = W1 + (size_t)w * 64 * 128 + c0;
    int tb = w << 6;
    float acc[4][4];
#pragma unroll
    for (int i = 0; i < 4; i++)
#pragma unroll
      for (int u = 0; u < 4; u++) acc[i][u] = 0.f;

    float4 wbuf[4];
#pragma unroll
    for (int p = 0; p < 4; p++)
      wbuf[p] = *(const float4*)(W1p + (size_t)p * 128);
#pragma unroll
    for (int t4 = 0; t4 < 16; t4++) {
      float4 cur0 = wbuf[0], cur1 = wbuf[1], cur2 = wbuf[2], cur3 = wbuf[3];
      if (t4 < 15) {
#pragma unroll
        for (int p = 0; p < 4; p++)
          wbuf[p] = *(const float4*)(W1p + (size_t)((t4 + 1) * 4 + p) * 128);
      }
#pragma unroll
      for (int p = 0; p < 4; p++) {
        int t = t4 * 4 + p;
        float4 wv = (p == 0) ? cur0 : (p == 1) ? cur1 : (p == 2) ? cur2 : cur3;
        float4 tv = *(const float4*)(&tstT[tb + t][4 * rh]);  // 2-addr bcast
        acc[0][0] += tv.x * wv.x; acc[0][1] += tv.x * wv.y; acc[0][2] += tv.x * wv.z; acc[0][3] += tv.x * wv.w;
        acc[1][0] += tv.y * wv.x; acc[1][1] += tv.y * wv.y; acc[1][2] += tv.y * wv.z; acc[1][3] += tv.y * wv.w;
        acc[2][0] += tv.z * wv.x; acc[2][1] += tv.z * wv.y; acc[2][2] += tv.z * wv.z; acc[2][3] += tv.z * wv.w;
        acc[3][0] += tv.w * wv.x; acc[3][1] += tv.w * wv.y; acc[3][2] += tv.w * wv.z; acc[3][3] += tv.w * wv.w;
      }
    }
#pragma unroll
    for (int i = 0; i < 4; i++) {
      *(float4*)(&part[w][4 * rh + i][c0]) =
          make_float4(acc[i][0], acc[i][1], acc[i][2], acc[i][3]);
    }
  }
  __syncthreads();

  // ---- merged combine + bias + residual + LN1. Wave w -> row w ----
  {
    float a0 = b1[lane] + xstT[lane][w];
    float a1 = b1[lane + 64] + xstT[lane + 64][w];
#pragma unroll
    for (int ko = 0; ko < 8; ko++) {
      a0 += part[ko][w][lane];        // conflict-free b32
      a1 += part[ko][w][lane + 64];
    }
    float s = a0 + a1, s2 = a0 * a0 + a1 * a1;
    for (int o = 32; o > 0; o >>= 1) {
      s += __shfl_xor(s, o, 64);
      s2 += __shfl_xor(s2, o, 64);
    }
    float mu = s * (1.f / 128.f);
    float var = s2 * (1.f / 128.f) - mu * mu;
    float rs = rsqrtf(var + 1e-5f);
    ys[w][lane] = (a0 - mu) * rs * g1[lane] + be1[lane];
    ys[w][lane + 64] = (a1 - mu) * rs * g1[lane + 64] + be1[lane + 64];
  }
  __syncthreads();

  // ---- transposed write: out (N,C,L); 8 consecutive l per c ----
  {
    int c = tid >> 2, tq = tid & 3;
    *(float2*)(out + ((size_t)n * 128 + c) * 512 + i0 + 2 * tq) =
        make_float2(ys[2 * tq][c], ys[2 * tq + 1][c]);
  }
}

// ---------------------------------------------------------------------------
extern "C" void kernel_launch(void* const* d_in, const int* in_sizes, int n_in,
                              void* d_out, int out_size, void* d_ws, size_t ws_size,
                              hipStream_t stream) {
  const float* x   = (const float*)d_in[0];
  const float* Wx  = (const float*)d_in[1];
  const float* Wt  = (const float*)d_in[2];
  const float* bh  = (const float*)d_in[3];
  const float* Wa  = (const float*)d_in[4];
  const float* ba  = (const float*)d_in[5];
  const float* W0  = (const float*)d_in[6];
  const float* b0  = (const float*)d_in[7];
  const float* W1  = (const float*)d_in[8];
  const float* b1  = (const float*)d_in[9];
  const float* g0  = (const float*)d_in[10];
  const float* be0 = (const float*)d_in[11];
  const float* g1  = (const float*)d_in[12];
  const float* be1 = (const float*)d_in[13];

  float* outx = (float*)d_out;           // N*C*L = 524288
  float* outa = outx + (size_t)524288;   // N*L*L = 2097152

  float* ws = (float*)d_ws;
  float* q  = ws;              // 262144
  float* k  = q + 262144;      // 262144

  prep_kernel<<<256, 512, 0, stream>>>(x, Wt, Wx, q, k);
  attn_ffn_fused_kernel<<<512, 512, 0, stream>>>(
      x, q, k, bh, Wa, ba, g0, be0, W0, b0, W1, b1, g1, be1, outa, outx);
}